// Round 2
// baseline (11548.341 us; speedup 1.0000x reference)
//
#include <hip/hip_runtime.h>

// Problem: B=256, T=512, H=512, O=2 relu-RNN. All inputs AND outputs fp32.
// d_out layout (fp32 elements): out[B,O]=512 | hidden[B,H]=131072 |
//   net_units[B,T,H]=67108864 | read_out_units[B,T,O]=262144
// d_ws: 2 x [B,H] fp32 ping-pong hidden-state buffers (1 MB).
//
// Persistent-kernel design: 256 blocks, 1/CU (145KB static LDS).
// Block (bg,jg): bg in 0..31 owns batches bg*8..+8, jg in 0..7 owns cols jg*64..+64.
// W_hh slice [64][512] staged in LDS ONCE. Per step the 8 jg-blocks of a bg
// exchange their h chunks through global hbuf with a per-bg flag counter
// (release fetch_add / bounded relaxed spin / acquire fence, agent scope).
// Launched cooperatively so co-residency is VALIDATED, not assumed; the spin
// is bounded so a pathological case degrades to wrong-answer, never GPU hang.

#define B_ 256
#define T_ 512
#define H_ 512
#define WSTRIDE 516   // 512+4: rows 16B-aligned, start bank 4j%32 -> balanced b128 reads

__global__ __launch_bounds__(256, 1) void rnn_persistent(
    const float* __restrict__ input,   // [B,T,2]
    const float* __restrict__ sigma,   // [1]
    const float* __restrict__ noise,   // [B,T,H]
    const float* __restrict__ W_in,    // [H,2]
    const float* __restrict__ b_in,    // [H]
    const float* __restrict__ W_hh,    // [H,H]
    const float* __restrict__ b_hh,    // [H]
    float* __restrict__ hbuf,          // [2,B,H] ping-pong (d_ws)
    unsigned int* __restrict__ flags,  // [32] per-bg monotonic counters (d_out head, memset 0)
    float* __restrict__ net)           // [B,T,H]
{
    __shared__ float w_s[64 * WSTRIDE];   // 132 KB: W_hh slice
    __shared__ float h_s[8 * H_];         // 16 KB: h_prev tile; first 8KB doubles as
                                          // the cross-wave reduce buffer (h_prev is
                                          // dead once the matvec partials are done)
    float* red = h_s;                     // [4*8][64] ks-partials (aliased)

    const int tid = threadIdx.x;
    const int bg  = blockIdx.x & 31;
    const int jg  = blockIdx.x >> 5;
    const int j   = tid & 63;
    const int ks  = tid >> 6;            // wave id 0..3 -> k-slice
    const int b0  = bg * 8;
    const int hj0 = jg * 64;
    const int hj  = hj0 + j;
    const int k0  = ks * 128;

    // ---- one-time: stage W_hh[hj0..hj0+63][0..511] into LDS ----
    for (int f = tid; f < 64 * 128; f += 256) {
        int r  = f >> 7;       // 0..63
        int c4 = f & 127;      // float4 col
        float4 v = ((const float4*)(W_hh + (size_t)(hj0 + r) * H_))[c4];
        *(float4*)&w_s[r * WSTRIDE + c4 * 4] = v;
    }
    // ---- h_0 = 0 ----
    for (int f = tid; f < 8 * 128; f += 256)
        ((float4*)h_s)[f] = make_float4(0.f, 0.f, 0.f, 0.f);

    // per-thread loop-invariant epilogue operands
    const float xw0 = W_in[2 * hj];
    const float xw1 = W_in[2 * hj + 1];
    const float bib = b_in[hj] + b_hh[hj];
    const float sg  = sigma[0];

    __syncthreads();

    for (int t = 0; t < T_; ++t) {
        // ---- prefetch epilogue operands (latency hidden under matvec) ----
        const int ba = b0 + ks;          // this thread's epilogue rows: ks, ks+4
        const int bb = b0 + ks + 4;
        float i0a = input[((size_t)ba * T_ + t) * 2 + 0];
        float i1a = input[((size_t)ba * T_ + t) * 2 + 1];
        float i0b = input[((size_t)bb * T_ + t) * 2 + 0];
        float i1b = input[((size_t)bb * T_ + t) * 2 + 1];
        float nza = noise[((size_t)ba * T_ + t) * H_ + hj];
        float nzb = noise[((size_t)bb * T_ + t) * H_ + hj];

        // ---- matvec partials over k in [k0, k0+128):
        // w read: per-lane b128, start bank 4j%32 (balanced);
        // h read: wave-uniform address -> LDS broadcast (cheap)
        float acc[8] = {0.f, 0.f, 0.f, 0.f, 0.f, 0.f, 0.f, 0.f};
        const float* wrow = &w_s[j * WSTRIDE + k0];
        const float* hrow = &h_s[k0];
        #pragma unroll 4
        for (int kk = 0; kk < 32; ++kk) {
            float4 w4 = *(const float4*)&wrow[kk * 4];
            #pragma unroll
            for (int b = 0; b < 8; ++b) {
                float4 h4 = *(const float4*)&hrow[b * H_ + kk * 4];
                acc[b] = fmaf(h4.x, w4.x, acc[b]);
                acc[b] = fmaf(h4.y, w4.y, acc[b]);
                acc[b] = fmaf(h4.z, w4.z, acc[b]);
                acc[b] = fmaf(h4.w, w4.w, acc[b]);
            }
        }

        __syncthreads();                 // h_prev reads done -> red may overwrite h_s
        #pragma unroll
        for (int b = 0; b < 8; ++b)
            red[(ks * 8 + b) * 64 + j] = acc[b];   // bank j%32, 2-way (free)
        __syncthreads();

        // ---- cross-ks reduce + epilogue; thread handles (b=ks, j) and (b=ks+4, j)
        float* hb = hbuf + (size_t)(t & 1) * B_ * H_;
        #pragma unroll
        for (int q = 0; q < 2; ++q) {
            int bl = ks + 4 * q;
            float v = red[(0 * 8 + bl) * 64 + j]
                    + red[(1 * 8 + bl) * 64 + j]
                    + red[(2 * 8 + bl) * 64 + j]
                    + red[(3 * 8 + bl) * 64 + j];
            float i0 = q ? i0b : i0a;
            float i1 = q ? i1b : i1a;
            float nz = q ? nzb : nza;
            v += i0 * xw0 + i1 * xw1 + bib + sg * nz;
            v = v > 0.f ? v : 0.f;
            hb[(size_t)(b0 + bl) * H_ + hj] = v;
            net[((size_t)(b0 + bl) * T_ + t) * H_ + hj] = v;
        }

        if (t == T_ - 1) break;   // last h stays in hbuf[1] (511 odd)

        // ---- 8-block group sync (release/acquire through device coherence) ----
        __syncthreads();          // drains vmcnt: all lanes' hb stores are in L2
        if (tid == 0) {
            __hip_atomic_fetch_add(&flags[bg], 1u, __ATOMIC_RELEASE,
                                   __HIP_MEMORY_SCOPE_AGENT);
            unsigned int target = 8u * (unsigned int)(t + 1);
            int guard = 1 << 16;  // bounded: degrade to wrong-answer, never hang
            while (__hip_atomic_load(&flags[bg], __ATOMIC_RELAXED,
                                     __HIP_MEMORY_SCOPE_AGENT) < target && --guard)
                __builtin_amdgcn_s_sleep(1);
        }
        __syncthreads();
        __builtin_amdgcn_fence(__ATOMIC_ACQUIRE, "agent");

        // ---- restage full h_t[8][512] (own chunk + 7 peers) into LDS ----
        for (int f = tid; f < 8 * 128; f += 256) {
            int b  = f >> 7;
            int c4 = f & 127;
            float4 v = *(const float4*)&hb[(size_t)(b0 + b) * H_ + c4 * 4];
            *(float4*)&h_s[b * H_ + c4 * 4] = v;
        }
        __syncthreads();
    }
}

// out[b,:] = h_last[b,:] @ W_fc^T + b_fc ; hidden[b,:] = h_last[b,:]
__global__ __launch_bounds__(256) void final_kernel(
    const float* __restrict__ hlast, // [B,H] fp32
    const float* __restrict__ W_fc,  // [O,H]
    const float* __restrict__ b_fc,  // [O]
    float* __restrict__ out,         // [B,O]
    float* __restrict__ hidden)      // [B,H]
{
    __shared__ float red[2][256];
    int b = blockIdx.x;
    int tid = threadIdx.x;
    float a0 = 0.f, a1 = 0.f;
    for (int h = tid; h < H_; h += 256) {
        float v = hlast[(size_t)b * H_ + h];
        hidden[(size_t)b * H_ + h] = v;
        a0 = fmaf(v, W_fc[h], a0);
        a1 = fmaf(v, W_fc[H_ + h], a1);
    }
    red[0][tid] = a0; red[1][tid] = a1;
    __syncthreads();
    for (int s = 128; s > 0; s >>= 1) {
        if (tid < s) {
            red[0][tid] += red[0][tid + s];
            red[1][tid] += red[1][tid + s];
        }
        __syncthreads();
    }
    if (tid == 0) {
        out[b * 2 + 0] = red[0][0] + b_fc[0];
        out[b * 2 + 1] = red[1][0] + b_fc[1];
    }
}

// read_out_units[b,t,:] = net[b,t,:] @ W_fc^T + b_fc. One wave per (b,t).
__global__ __launch_bounds__(256) void readout_kernel(
    const float* __restrict__ net,  // [B*T, H] fp32
    const float* __restrict__ W_fc, // [O,H] fp32
    const float* __restrict__ b_fc, // [O]
    float* __restrict__ ro)         // [B*T, O]
{
    int wave = threadIdx.x >> 6;
    int lane = threadIdx.x & 63;
    int idx  = blockIdx.x * 4 + wave;   // flattened (b,t)

    const float4* nrow = (const float4*)(net + (size_t)idx * H_);
    float4 n0 = nrow[lane * 2];
    float4 n1 = nrow[lane * 2 + 1];
    float4 w0a = ((const float4*)W_fc)[lane * 2];
    float4 w0b = ((const float4*)W_fc)[lane * 2 + 1];
    float4 w1a = ((const float4*)(W_fc + H_))[lane * 2];
    float4 w1b = ((const float4*)(W_fc + H_))[lane * 2 + 1];

    float a0, a1;
    a0  = n0.x * w0a.x + n0.y * w0a.y + n0.z * w0a.z + n0.w * w0a.w;
    a0 += n1.x * w0b.x + n1.y * w0b.y + n1.z * w0b.z + n1.w * w0b.w;
    a1  = n0.x * w1a.x + n0.y * w1a.y + n0.z * w1a.z + n0.w * w1a.w;
    a1 += n1.x * w1b.x + n1.y * w1b.y + n1.z * w1b.z + n1.w * w1b.w;

    #pragma unroll
    for (int off = 32; off > 0; off >>= 1) {
        a0 += __shfl_down(a0, off);
        a1 += __shfl_down(a1, off);
    }
    if (lane == 0) {
        ro[(size_t)idx * 2 + 0] = a0 + b_fc[0];
        ro[(size_t)idx * 2 + 1] = a1 + b_fc[1];
    }
}

extern "C" void kernel_launch(void* const* d_in, const int* in_sizes, int n_in,
                              void* d_out, int out_size, void* d_ws, size_t ws_size,
                              hipStream_t stream)
{
    const float* input = (const float*)d_in[0];
    const float* sigma = (const float*)d_in[1];
    const float* noise = (const float*)d_in[2];
    const float* W_in  = (const float*)d_in[3];
    const float* b_in  = (const float*)d_in[4];
    const float* W_hh  = (const float*)d_in[5];
    const float* b_hh  = (const float*)d_in[6];
    const float* W_fc  = (const float*)d_in[7];
    const float* b_fc  = (const float*)d_in[8];

    float* out    = (float*)d_out;                   // [B,O]
    float* hidden = out + (size_t)B_ * 2;            // [B,H]
    float* net    = hidden + (size_t)B_ * H_;        // [B,T,H]
    float* ro     = net + (size_t)B_ * T_ * H_;      // [B,T,O]

    float* hbuf   = (float*)d_ws;                    // [2,B,H] ping-pong

    // Sync flags: borrow the out[B,O] region (512 floats) during the persistent
    // kernel; final_kernel fully rewrites it afterwards. Zeroed per replay.
    unsigned int* flags = (unsigned int*)d_out;
    hipMemsetAsync(flags, 0, 32 * sizeof(unsigned int), stream);

    // Cooperative launch: validates 256-block co-residency instead of hanging.
    void* args[] = {(void*)&input, (void*)&sigma, (void*)&noise, (void*)&W_in,
                    (void*)&b_in,  (void*)&W_hh,  (void*)&b_hh,  (void*)&hbuf,
                    (void*)&flags, (void*)&net};
    hipError_t err = hipLaunchCooperativeKernel((const void*)rnn_persistent,
                                                dim3(256), dim3(256), args, 0, stream);
    if (err != hipSuccess) {
        (void)hipGetLastError();   // clear; fall back to plain launch
        rnn_persistent<<<256, 256, 0, stream>>>(input, sigma, noise, W_in, b_in,
                                                W_hh, b_hh, hbuf, flags, net);
    }

    // T-1 = 511 is odd -> h_last in hbuf[1]
    final_kernel<<<B_, 256, 0, stream>>>(hbuf + (size_t)B_ * H_, W_fc, b_fc, out, hidden);
    readout_kernel<<<(B_ * T_) / 4, 256, 0, stream>>>(net, W_fc, b_fc, ro);
}

// Round 3
// 4045.504 us; speedup vs baseline: 2.8546x; 2.8546x over previous
//
#include <hip/hip_runtime.h>

// Problem: B=256, T=512, H=512, O=2 relu-RNN. All inputs AND outputs fp32.
// d_out layout (fp32 elements): out[B,O]=512 | hidden[B,H]=131072 |
//   net_units[B,T,H]=67108864 | read_out_units[B,T,O]=262144
// d_ws: 2 x [B,H] fp32 ping-pong hidden-state buffers (1 MB).
//
// Persistent-kernel design: 256 blocks x 512 threads, 1 block/CU (145KB LDS).
// Block (bg,jg): bg in 0..31 owns batches bg*8..+8, jg in 0..7 owns cols jg*64..+64.
// W_hh slice [64][512] staged in LDS ONCE. Per step the 8 jg-blocks of a bg
// exchange h chunks through hbuf.
//
// SYNC (the round-2 lesson): agent-scope RELEASE/ACQUIRE fences lower to
// buffer_wbl2/buffer_inv (full per-XCD 4MB L2 sweeps) -> ~20us/step. Instead,
// only the exchanged data itself is made coherent: hb stores/loads are
// per-access agent-scope relaxed atomics (sc1: complete at / read from IF$,
// the cross-XCD coherence point), ordered by per-wave s_waitcnt vmcnt(0)
// before the flag fetch_add. No fence instructions -> no L2 sweeps.
// net stores stay normal cached writes (read only after kernel end).

#define B_ 256
#define T_ 512
#define H_ 512
#define WSTRIDE 516   // 512+4: rows 16B-aligned, start bank 4j%32 -> balanced b128 reads

__global__ __launch_bounds__(512, 1) void rnn_persistent(
    const float* __restrict__ input,   // [B,T,2]
    const float* __restrict__ sigma,   // [1]
    const float* __restrict__ noise,   // [B,T,H]
    const float* __restrict__ W_in,    // [H,2]
    const float* __restrict__ b_in,    // [H]
    const float* __restrict__ W_hh,    // [H,H]
    const float* __restrict__ b_hh,    // [H]
    float* __restrict__ hbuf,          // [2,B,H] ping-pong (d_ws)
    unsigned int* __restrict__ flags,  // [32] per-bg monotonic counters (d_out head, memset 0)
    float* __restrict__ net)           // [B,T,H]
{
    __shared__ float w_s[64 * WSTRIDE];   // 132 KB: W_hh slice
    __shared__ float h_s[8 * H_];         // 16 KB: h_prev tile; aliased as the
                                          // [8ks][8b][64j] reduce buffer (h_prev is
                                          // dead once matvec partials are done)
    float* red = h_s;

    const int tid = threadIdx.x;
    const int bg  = blockIdx.x & 31;
    const int jg  = blockIdx.x >> 5;
    const int j   = tid & 63;
    const int ks  = tid >> 6;            // wave id 0..7 -> k-slice / epilogue batch-row
    const int b0  = bg * 8;
    const int hj0 = jg * 64;
    const int hj  = hj0 + j;
    const int k0  = ks * 64;

    // ---- one-time: stage W_hh[hj0..hj0+63][0..511] into LDS ----
    for (int f = tid; f < 64 * 128; f += 512) {
        int r  = f >> 7;       // 0..63
        int c4 = f & 127;      // float4 col
        float4 v = ((const float4*)(W_hh + (size_t)(hj0 + r) * H_))[c4];
        *(float4*)&w_s[r * WSTRIDE + c4 * 4] = v;
    }
    // ---- h_0 = 0 ----
    for (int f = tid; f < 8 * 128; f += 512)
        ((float4*)h_s)[f] = make_float4(0.f, 0.f, 0.f, 0.f);

    // per-thread loop-invariant epilogue operands (this thread's output = (b0+ks, hj))
    const float xw0 = W_in[2 * hj];
    const float xw1 = W_in[2 * hj + 1];
    const float bib = b_in[hj] + b_hh[hj];
    const float sg  = sigma[0];
    const int   bo  = b0 + ks;           // epilogue batch row

    __syncthreads();

    for (int t = 0; t < T_; ++t) {
        // ---- prefetch epilogue operands (latency hidden under matvec) ----
        float i0 = input[((size_t)bo * T_ + t) * 2 + 0];
        float i1 = input[((size_t)bo * T_ + t) * 2 + 1];
        float nz = noise[((size_t)bo * T_ + t) * H_ + hj];

        // ---- matvec partials over k in [k0, k0+64):
        // w read: per-lane b128, start bank 4j%32 (balanced, 8 dwords/bank);
        // h read: wave-uniform address -> LDS broadcast (cheap)
        float acc[8] = {0.f, 0.f, 0.f, 0.f, 0.f, 0.f, 0.f, 0.f};
        const float* wrow = &w_s[j * WSTRIDE + k0];
        const float* hrow = &h_s[k0];
        #pragma unroll 4
        for (int kk = 0; kk < 16; ++kk) {
            float4 w4 = *(const float4*)&wrow[kk * 4];
            #pragma unroll
            for (int b = 0; b < 8; ++b) {
                float4 h4 = *(const float4*)&hrow[b * H_ + kk * 4];
                acc[b] = fmaf(h4.x, w4.x, acc[b]);
                acc[b] = fmaf(h4.y, w4.y, acc[b]);
                acc[b] = fmaf(h4.z, w4.z, acc[b]);
                acc[b] = fmaf(h4.w, w4.w, acc[b]);
            }
        }

        __syncthreads();                 // h_prev reads done -> red may overwrite h_s
        #pragma unroll
        for (int b = 0; b < 8; ++b)
            red[(ks * 8 + b) * 64 + j] = acc[b];   // 64 consecutive dwords/wave: free
        __syncthreads();

        // ---- cross-ks reduce + epilogue: thread owns output (bo, hj) ----
        float v = 0.f;
        #pragma unroll
        for (int s = 0; s < 8; ++s)
            v += red[(s * 8 + ks) * 64 + j];
        v += i0 * xw0 + i1 * xw1 + bib + sg * nz;
        v = v > 0.f ? v : 0.f;

        float* hb = hbuf + (size_t)(t & 1) * B_ * H_;
        // agent-coherent store: completes at IF$ (cross-XCD visible, no fence needed)
        __hip_atomic_store(&hb[(size_t)bo * H_ + hj], v,
                           __ATOMIC_RELAXED, __HIP_MEMORY_SCOPE_AGENT);
        net[((size_t)bo * T_ + t) * H_ + hj] = v;   // normal cached store

        if (t == T_ - 1) break;   // last h stays in hbuf[1] (511 odd)

        // ---- hand-rolled release: every wave drains its own stores, then barrier,
        //      then one flag bump (relaxed RMW always goes to the coherence point)
        asm volatile("s_waitcnt vmcnt(0)" ::: "memory");
        __syncthreads();
        if (tid == 0) {
            __hip_atomic_fetch_add(&flags[bg], 1u, __ATOMIC_RELAXED,
                                   __HIP_MEMORY_SCOPE_AGENT);
            unsigned int target = 8u * (unsigned int)(t + 1);
            int guard = 1 << 16;  // bounded: degrade to wrong-answer, never GPU hang
            while (__hip_atomic_load(&flags[bg], __ATOMIC_RELAXED,
                                     __HIP_MEMORY_SCOPE_AGENT) < target && --guard)
                __builtin_amdgcn_s_sleep(1);
        }
        __syncthreads();

        // ---- restage h_t[8][512]: agent-coherent loads (read from IF$, bypass
        //      possibly-stale local L2 copy from step t-2's use of this buffer)
        for (int f = tid; f < 8 * 512; f += 512) {
            int b = f >> 9;
            int c = f & 511;
            h_s[b * H_ + c] = __hip_atomic_load(&hb[(size_t)(b0 + b) * H_ + c],
                                                __ATOMIC_RELAXED,
                                                __HIP_MEMORY_SCOPE_AGENT);
        }
        __syncthreads();
    }
}

// out[b,:] = h_last[b,:] @ W_fc^T + b_fc ; hidden[b,:] = h_last[b,:]
__global__ __launch_bounds__(256) void final_kernel(
    const float* __restrict__ hlast, // [B,H] fp32
    const float* __restrict__ W_fc,  // [O,H]
    const float* __restrict__ b_fc,  // [O]
    float* __restrict__ out,         // [B,O]
    float* __restrict__ hidden)      // [B,H]
{
    __shared__ float red[2][256];
    int b = blockIdx.x;
    int tid = threadIdx.x;
    float a0 = 0.f, a1 = 0.f;
    for (int h = tid; h < H_; h += 256) {
        float v = hlast[(size_t)b * H_ + h];
        hidden[(size_t)b * H_ + h] = v;
        a0 = fmaf(v, W_fc[h], a0);
        a1 = fmaf(v, W_fc[H_ + h], a1);
    }
    red[0][tid] = a0; red[1][tid] = a1;
    __syncthreads();
    for (int s = 128; s > 0; s >>= 1) {
        if (tid < s) {
            red[0][tid] += red[0][tid + s];
            red[1][tid] += red[1][tid + s];
        }
        __syncthreads();
    }
    if (tid == 0) {
        out[b * 2 + 0] = red[0][0] + b_fc[0];
        out[b * 2 + 1] = red[1][0] + b_fc[1];
    }
}

// read_out_units[b,t,:] = net[b,t,:] @ W_fc^T + b_fc. One wave per (b,t).
__global__ __launch_bounds__(256) void readout_kernel(
    const float* __restrict__ net,  // [B*T, H] fp32
    const float* __restrict__ W_fc, // [O,H] fp32
    const float* __restrict__ b_fc, // [O]
    float* __restrict__ ro)         // [B*T, O]
{
    int wave = threadIdx.x >> 6;
    int lane = threadIdx.x & 63;
    int idx  = blockIdx.x * 4 + wave;   // flattened (b,t)

    const float4* nrow = (const float4*)(net + (size_t)idx * H_);
    float4 n0 = nrow[lane * 2];
    float4 n1 = nrow[lane * 2 + 1];
    float4 w0a = ((const float4*)W_fc)[lane * 2];
    float4 w0b = ((const float4*)W_fc)[lane * 2 + 1];
    float4 w1a = ((const float4*)(W_fc + H_))[lane * 2];
    float4 w1b = ((const float4*)(W_fc + H_))[lane * 2 + 1];

    float a0, a1;
    a0  = n0.x * w0a.x + n0.y * w0a.y + n0.z * w0a.z + n0.w * w0a.w;
    a0 += n1.x * w0b.x + n1.y * w0b.y + n1.z * w0b.z + n1.w * w0b.w;
    a1  = n0.x * w1a.x + n0.y * w1a.y + n0.z * w1a.z + n0.w * w1a.w;
    a1 += n1.x * w1b.x + n1.y * w1b.y + n1.z * w1b.z + n1.w * w1b.w;

    #pragma unroll
    for (int off = 32; off > 0; off >>= 1) {
        a0 += __shfl_down(a0, off);
        a1 += __shfl_down(a1, off);
    }
    if (lane == 0) {
        ro[(size_t)idx * 2 + 0] = a0 + b_fc[0];
        ro[(size_t)idx * 2 + 1] = a1 + b_fc[1];
    }
}

extern "C" void kernel_launch(void* const* d_in, const int* in_sizes, int n_in,
                              void* d_out, int out_size, void* d_ws, size_t ws_size,
                              hipStream_t stream)
{
    const float* input = (const float*)d_in[0];
    const float* sigma = (const float*)d_in[1];
    const float* noise = (const float*)d_in[2];
    const float* W_in  = (const float*)d_in[3];
    const float* b_in  = (const float*)d_in[4];
    const float* W_hh  = (const float*)d_in[5];
    const float* b_hh  = (const float*)d_in[6];
    const float* W_fc  = (const float*)d_in[7];
    const float* b_fc  = (const float*)d_in[8];

    float* out    = (float*)d_out;                   // [B,O]
    float* hidden = out + (size_t)B_ * 2;            // [B,H]
    float* net    = hidden + (size_t)B_ * H_;        // [B,T,H]
    float* ro     = net + (size_t)B_ * T_ * H_;      // [B,T,O]

    float* hbuf   = (float*)d_ws;                    // [2,B,H] ping-pong

    // Sync flags: borrow the out[B,O] region (512 floats) during the persistent
    // kernel; final_kernel fully rewrites it afterwards. Zeroed per replay.
    unsigned int* flags = (unsigned int*)d_out;
    hipMemsetAsync(flags, 0, 32 * sizeof(unsigned int), stream);

    // Cooperative launch: validates 256-block co-residency instead of hanging.
    void* args[] = {(void*)&input, (void*)&sigma, (void*)&noise, (void*)&W_in,
                    (void*)&b_in,  (void*)&W_hh,  (void*)&b_hh,  (void*)&hbuf,
                    (void*)&flags, (void*)&net};
    hipError_t err = hipLaunchCooperativeKernel((const void*)rnn_persistent,
                                                dim3(256), dim3(512), args, 0, stream);
    if (err != hipSuccess) {
        (void)hipGetLastError();   // clear; fall back to plain launch
        rnn_persistent<<<256, 512, 0, stream>>>(input, sigma, noise, W_in, b_in,
                                                W_hh, b_hh, hbuf, flags, net);
    }

    // T-1 = 511 is odd -> h_last in hbuf[1]
    final_kernel<<<B_, 256, 0, stream>>>(hbuf + (size_t)B_ * H_, W_fc, b_fc, out, hidden);
    readout_kernel<<<(B_ * T_) / 4, 256, 0, stream>>>(net, W_fc, b_fc, ro);
}